// Round 1
// baseline (892.131 us; speedup 1.0000x reference)
//
#include <hip/hip_runtime.h>
#include <math.h>

#define RR 64
#define DD 256
#define CAP 6144

// ---------- helpers ----------

__device__ __forceinline__ void get_mu_istd(const double* sums, int N, float& fmu, float& istd) {
  double M = (double)RR * (double)N;
  double mu = sums[0] / M;
  double var = (sums[1] - sums[0] * sums[0] / M) / (M - 1.0);
  fmu = (float)mu;
  istd = (float)(1.0 / sqrt(var));
}

// monotone float<->uint mapping for atomicMax on signed floats
__device__ __forceinline__ unsigned fmap(float f) {
  unsigned b = __float_as_uint(f);
  return (b & 0x80000000u) ? ~b : (b | 0x80000000u);
}
__device__ __forceinline__ float funmap(unsigned u) {
  unsigned b = (u & 0x80000000u) ? (u & 0x7fffffffu) : ~u;
  return __uint_as_float(b);
}

// async global->LDS, 16B per lane. LDS dest = wave-uniform base + lane*16.
__device__ __forceinline__ void cp16(const void* g, void* l) {
  __builtin_amdgcn_global_load_lds((const __attribute__((address_space(1))) void*)g,
                                   (__attribute__((address_space(3))) void*)l, 16, 0, 0);
}

// ---------- K_mask: per-block dtype sniff (same 4KB window -> consistent) + pack ----------

__global__ __launch_bounds__(256) void k_mask(const void* __restrict__ maskp,
                                              unsigned long long* __restrict__ mbits,
                                              int N) {
  __shared__ int f;
  int tid = threadIdx.x;
  if (tid == 0) f = 0;
  __syncthreads();
  {
    const unsigned* mw = (const unsigned*)maskp;
    int mode = 0;
    for (int i = tid; i < 4096; i += 256) {
      unsigned v = mw[i];
      if (v == 0x3f800000u) mode = 2;
      else if (v > 1u && mode != 2) mode = 1;
    }
    if (mode) atomicMax(&f, mode);
  }
  __syncthreads();
  const int mode = f;

  int n = blockIdx.x * 256 + tid;
  if (n >= N) return;
  unsigned long long b = 0;
  if (mode == 1) {
    const unsigned char* m = (const unsigned char*)maskp;
#pragma unroll
    for (int r = 0; r < RR; ++r)
      b |= (unsigned long long)(m[(size_t)r * N + n] != 0) << r;
  } else if (mode == 2) {
    const float* m = (const float*)maskp;
#pragma unroll
    for (int r = 0; r < RR; ++r)
      b |= (unsigned long long)(m[(size_t)r * N + n] != 0.f) << r;
  } else {
    const int* m = (const int*)maskp;
#pragma unroll
    for (int r = 0; r < RR; ++r)
      b |= (unsigned long long)(m[(size_t)r * N + n] != 0) << r;
  }
  mbits[n] = b;
}

// ---------- K1: hsW = hs @ W   [64 x 256] ----------

__global__ __launch_bounds__(256) void k_hsw(const float* __restrict__ hs,
                                             const float* __restrict__ W,
                                             float* __restrict__ hsW) {
  int i = blockIdx.x;
  int j = threadIdx.x;
  float acc = 0.f;
  for (int k = 0; k < DD; ++k) acc = fmaf(hs[i * DD + k], W[k * DD + j], acc);
  hsW[i * DD + j] = acc;
}

// ---------- K2: scores GEMM ----------
// Round-6 change: 2-phase software pipeline (guide T3-minimum).
//  - K-chunk 32 -> 16; double-buffered LDS = 2*(16KB es + 4KB hsW) = 40.0KB
//    -> 4 blocks/CU (was 3 at 45.5KB).
//  - Staging via global_load_lds width=16 (no VGPR roundtrip, no staging VALU).
//  - STAGE(t+1) issued BEFORE compute(t); one barrier per chunk; the barrier's
//    implicit vmcnt(0) drain lands after ~2048 FMA cycles -> HBM latency hidden.
//  - global_load_lds needs a LINEAR LDS dest (no +pad), so es reads are
//    de-conflicted by rule #21: inverse-swizzle the GLOBAL source granule and
//    apply the same XOR on the read address (granule ^= (col>>1)&3) -> 2-way
//    (free). hsW reads are wave-uniform broadcasts (conflict-free).
// Numerics: identical k-accumulation order as round-5 -> bitwise-same scores.

__global__ __launch_bounds__(256, 4) void k_scores(const float* __restrict__ es,
                                                   const float* __restrict__ hsW,
                                                   const unsigned long long* __restrict__ mbits,
                                                   float* __restrict__ scores,
                                                   float* __restrict__ colmax,
                                                   int* __restrict__ colargmax,
                                                   double* __restrict__ sums,
                                                   unsigned* __restrict__ rowmax_u,
                                                   int N) {
  // layout (dwords): [0..4095] es buf0 | [4096..8191] es buf1
  //                  [8192..9215] w buf0 | [9216..10239] w buf1
  // stats phase reuses [0..5135].
  __shared__ float lds[10240];
  const int tid = threadIdx.x;
  const int lane = tid & 63;
  const int ty = __builtin_amdgcn_readfirstlane(tid >> 6);
  const int n0 = blockIdx.x * 256;
  const int R0 = ty * 16;
  const int nb = n0 + lane;    // col c -> nb + 64*c

  float4 acc[16];
#pragma unroll
  for (int i = 0; i < 16; ++i) acc[i] = make_float4(0.f, 0.f, 0.f, 0.f);

  // ---- stage one 16-k chunk into buffer b (async) ----
  // es tile: [256 cols][16 k] dwords, 16B-granule XOR-swizzled by (c>>1)&3.
  // w tile:  [64 rows][16 k] dwords, linear.
  auto stage = [&](int buf, int kc) {
#pragma unroll
    for (int j = 0; j < 4; ++j) {
      const int s = ty * 4 + j;                 // 1KB slot 0..15 (uniform)
      const int c = s * 16 + (lane >> 2);       // col 0..255
      const int rr = min(n0 + c, N - 1);
      const int q = (lane & 3) ^ ((c >> 1) & 3);  // inverse-swizzled source granule
      float* ldsb = lds + buf * 4096 + s * 256;   // wave-uniform base
      cp16(es + (size_t)rr * DD + kc + q * 4, ldsb);
    }
    {
      const int row = R0 + (lane >> 2);
      const int q = lane & 3;
      float* ldsb = lds + 8192 + buf * 1024 + ty * 256;  // wave-uniform base
      cp16(hsW + row * DD + kc + q * 4, ldsb);
    }
  };

  stage(0, 0);
  asm volatile("s_waitcnt vmcnt(0)" ::: "memory");
  __syncthreads();

  for (int kc = 0; kc < DD; kc += 16) {
    const int cur = (kc >> 4) & 1;
    if (kc + 16 < DD) stage(cur ^ 1, kc + 16);   // prefetch next chunk (async)

    const float* eb = lds + cur * 4096;
    const float* wb = lds + 8192 + cur * 1024;
    const int csw = (lane >> 1) & 3;             // read-side XOR term (same for all 4 cols)
#pragma unroll
    for (int k = 0; k < 16; k += 4) {
      const int swo = (((k >> 2) ^ csw) << 2);
      const float4 e0 = *(const float4*)(eb + (lane       ) * 16 + swo);
      const float4 e1 = *(const float4*)(eb + (lane +  64 ) * 16 + swo);
      const float4 e2 = *(const float4*)(eb + (lane + 128 ) * 16 + swo);
      const float4 e3 = *(const float4*)(eb + (lane + 192 ) * 16 + swo);
#pragma unroll
      for (int i = 0; i < 16; ++i) {
        const float4 w = *(const float4*)(wb + (R0 + i) * 16 + k);  // uniform -> broadcast
        acc[i].x = fmaf(w.x, e0.x, fmaf(w.y, e0.y, fmaf(w.z, e0.z, fmaf(w.w, e0.w, acc[i].x))));
        acc[i].y = fmaf(w.x, e1.x, fmaf(w.y, e1.y, fmaf(w.z, e1.z, fmaf(w.w, e1.w, acc[i].y))));
        acc[i].z = fmaf(w.x, e2.x, fmaf(w.y, e2.y, fmaf(w.z, e2.z, fmaf(w.w, e2.w, acc[i].z))));
        acc[i].w = fmaf(w.x, e3.x, fmaf(w.y, e3.y, fmaf(w.z, e3.z, fmaf(w.w, e3.w, acc[i].w))));
      }
    }
    // drain prefetch + protect buffer swap (single barrier per chunk)
    asm volatile("s_waitcnt vmcnt(0)" ::: "memory");
    __syncthreads();
  }

  // ---- col validity ----
  bool val[4];
#pragma unroll
  for (int c = 0; c < 4; ++c) val[c] = (nb + 64 * c) < N;

  // ---- store scores ----
#pragma unroll
  for (int i = 0; i < 16; ++i) {
    float* dst = scores + (size_t)(R0 + i) * N + nb;
    float v[4] = {acc[i].x, acc[i].y, acc[i].z, acc[i].w};
#pragma unroll
    for (int c = 0; c < 4; ++c)
      if (val[c]) dst[64 * c] = v[c];
  }

  // ---- mask bits for my 4 cols ----
  unsigned long long mb[4];
#pragma unroll
  for (int c = 0; c < 4; ++c) mb[c] = val[c] ? mbits[nb + 64 * c] : 0ull;

  // ---- per-col partials over my 16 rows + fused row-max reductions ----
  float ps1[4], ps2[4], pcm[4], pbv[4];
  int pbr[4];
#pragma unroll
  for (int c = 0; c < 4; ++c) { ps1[c] = 0.f; ps2[c] = 0.f; pcm[c] = -INFINITY; pbv[c] = -INFINITY; pbr[c] = -1; }

#pragma unroll
  for (int i = 0; i < 16; ++i) {
    const int rrow = R0 + i;
    float v[4] = {acc[i].x, acc[i].y, acc[i].z, acc[i].w};
    float q = -INFINITY, qm = -INFINITY;
#pragma unroll
    for (int c = 0; c < 4; ++c) {
      ps1[c] += v[c];
      ps2[c] = fmaf(v[c], v[c], ps2[c]);
      pcm[c] = fmaxf(pcm[c], v[c]);
      bool bit = (mb[c] >> rrow) & 1ull;
      if (bit && (v[c] > pbv[c])) { pbv[c] = v[c]; pbr[c] = rrow; }
      float qv = val[c] ? v[c] : -INFINITY;
      q = fmaxf(q, qv);
      if (bit) qm = fmaxf(qm, qv);
    }
#pragma unroll
    for (int o = 32; o > 0; o >>= 1) {
      q = fmaxf(q, __shfl_down(q, o));
      qm = fmaxf(qm, __shfl_down(qm, o));
    }
    if (lane == 0) {
      atomicMax(rowmax_u + rrow, fmap(q));
      atomicMax(rowmax_u + 64 + rrow, fmap(qm));
    }
  }

  // ---- cross-wave col-stat combine via LDS (reuse es buffers) ----
  __syncthreads();
  float* Ls1 = lds;
  float* Ls2 = lds + 1024;
  float* Lcm = lds + 2048;
  float* Lbv = lds + 3072;
  int* Lbr = (int*)(lds + 4096);
  double* red = (double*)(lds + 5120);
#pragma unroll
  for (int c = 0; c < 4; ++c) {
    int col = lane + 64 * c;
    Ls1[ty * 256 + col] = ps1[c];
    Ls2[ty * 256 + col] = ps2[c];
    Lcm[ty * 256 + col] = pcm[c];
    Lbv[ty * 256 + col] = pbv[c];
    Lbr[ty * 256 + col] = pbr[c];
  }
  __syncthreads();

  const int n = n0 + tid;
  float s1 = 0.f, s2 = 0.f;
  if (n < N) {
    s1 = Ls1[tid] + Ls1[256 + tid] + Ls1[512 + tid] + Ls1[768 + tid];
    s2 = Ls2[tid] + Ls2[256 + tid] + Ls2[512 + tid] + Ls2[768 + tid];
    float cm = fmaxf(fmaxf(Lcm[tid], Lcm[256 + tid]), fmaxf(Lcm[512 + tid], Lcm[768 + tid]));
    colmax[n] = cm;
    float bv = -INFINITY;
    int br = -1;
#pragma unroll
    for (int w2 = 0; w2 < 4; ++w2) {
      float b = Lbv[w2 * 256 + tid];
      if (b > bv) { bv = b; br = Lbr[w2 * 256 + tid]; }
    }
    colargmax[n] = br;
  }

  double d1 = (double)s1, d2 = (double)s2;
#pragma unroll
  for (int o = 32; o > 0; o >>= 1) {
    d1 += __shfl_down(d1, o);
    d2 += __shfl_down(d2, o);
  }
  if ((tid & 63) == 0) { red[ty * 2] = d1; red[ty * 2 + 1] = d2; }
  __syncthreads();
  if (tid == 0) {
    atomicAdd(&sums[0], red[0] + red[2] + red[4] + red[6]);
    atomicAdd(&sums[1], red[1] + red[3] + red[5] + red[7]);
  }
}

// ---------- K4: fused column pass: collse + row exp-sums + candidate scatter ----------

__global__ __launch_bounds__(256) void k_colpass(const float* __restrict__ scores,
                                                 const float* __restrict__ colmax,
                                                 const int* __restrict__ colargmax,
                                                 const unsigned long long* __restrict__ mbits,
                                                 const double* __restrict__ sums,
                                                 const unsigned* __restrict__ rowmax_u,
                                                 float* __restrict__ collse,
                                                 float* __restrict__ rowacc,
                                                 int* __restrict__ cnt,
                                                 float* __restrict__ candx,
                                                 int* __restrict__ candn,
                                                 int N) {
  __shared__ float rmS[64], rmmS[64];
  __shared__ float rpu[64 * 4], rpm[64 * 4];
  __shared__ int lcnt[64], lbase[64];
  const int tid = threadIdx.x, lane = tid & 63, ty = tid >> 6;
  if (tid < 64) {
    rmS[tid] = funmap(rowmax_u[tid]);
    rmmS[tid] = funmap(rowmax_u[64 + tid]);
    lcnt[tid] = 0;
  }
  __syncthreads();
  const int n = blockIdx.x * 256 + tid;
  const bool valid = n < N;
  float fmu, istd;
  get_mu_istd(sums, N, fmu, istd);
  const float cm = valid ? colmax[n] : 0.f;
  const int br = valid ? colargmax[n] : -1;
  const unsigned long long mbn = valid ? mbits[n] : 0ull;
  float colsum = 0.f, xbr = 0.f;

  for (int r = 0; r < RR; ++r) {
    float x = valid ? scores[(size_t)r * N + n] : 0.f;
    if (r == br) xbr = x;
    if (valid) colsum += expf((x - cm) * istd);
    float eu = valid ? expf((x - rmS[r]) * istd) : 0.f;
    float em = (valid && ((mbn >> r) & 1ull)) ? expf((x - rmmS[r]) * istd) : 0.f;
#pragma unroll
    for (int o = 32; o > 0; o >>= 1) {
      eu += __shfl_down(eu, o);
      em += __shfl_down(em, o);
    }
    if (lane == 0) { rpu[r * 4 + ty] = eu; rpm[r * 4 + ty] = em; }
  }

  if (valid) collse[n] = logf(colsum);
  int lpos = 0;
  if (br >= 0) lpos = atomicAdd(&lcnt[br], 1);
  __syncthreads();
  if (tid < 64) {
    float su = rpu[tid * 4] + rpu[tid * 4 + 1] + rpu[tid * 4 + 2] + rpu[tid * 4 + 3];
    float sm = rpm[tid * 4] + rpm[tid * 4 + 1] + rpm[tid * 4 + 2] + rpm[tid * 4 + 3];
    atomicAdd(&rowacc[tid], su);
    atomicAdd(&rowacc[64 + tid], sm);
    int c = lcnt[tid];
    lbase[tid] = c ? atomicAdd(&cnt[tid], c) : 0;
  }
  __syncthreads();
  if (br >= 0) {
    int pos = lbase[br] + lpos;
    if (pos < CAP) {
      candx[(size_t)br * CAP + pos] = xbr;
      candn[(size_t)br * CAP + pos] = n;
    }
  }
}

// ---------- K3b: finalize row stats ----------

__global__ void k_rowfin(const float* __restrict__ rowacc,
                         const unsigned* __restrict__ rowmax_u,
                         float* __restrict__ rowstats) {
  int r = threadIdx.x;  // 64
  rowstats[r] = funmap(rowmax_u[r]);
  rowstats[64 + r] = logf(rowacc[r]);
  rowstats[128 + r] = funmap(rowmax_u[64 + r]);
  rowstats[192 + r] = rowacc[64 + r];
}

// ---------- K5: per-row top-50 (prob desc, index asc), 512 threads ----------

__global__ __launch_bounds__(512) void k_topk(const int* __restrict__ cnt,
                                              const float* __restrict__ candx,
                                              const int* __restrict__ candn,
                                              const double* __restrict__ sums,
                                              const float* __restrict__ rowstats,
                                              float* __restrict__ out,
                                              int* __restrict__ seln,
                                              int N, int NO) {
  int r = blockIdx.x, tid = threadIdx.x;
  __shared__ float sp[CAP];
  __shared__ int sn[CAP];
  __shared__ float wp[8];
  __shared__ int wn[8], wi[8];
  int c = min(cnt[r], CAP);
  float fmu, istd;
  get_mu_istd(sums, N, fmu, istd);
  const float rmm = rowstats[128 + r];
  const float lm = rowstats[192 + r];
  for (int i = tid; i < c; i += 512) {
    float xv = candx[(size_t)r * CAP + i];
    sp[i] = fmaxf(expf((xv - rmm) * istd) / lm, 1e-6f);
    sn[i] = candn[(size_t)r * CAP + i];
  }
  __syncthreads();
  for (int j = 0; j < NO; ++j) {
    float bp = -1.f;
    int bn = 0x7fffffff, bi = -1;
    for (int i = tid; i < c; i += 512) {
      float p = sp[i];
      int nn = sn[i];
      if (p > bp || (p == bp && nn < bn)) { bp = p; bn = nn; bi = i; }
    }
#pragma unroll
    for (int o = 32; o > 0; o >>= 1) {
      float p2 = __shfl_down(bp, o);
      int n2 = __shfl_down(bn, o);
      int i2 = __shfl_down(bi, o);
      if (p2 > bp || (p2 == bp && n2 < bn)) { bp = p2; bn = n2; bi = i2; }
    }
    if ((tid & 63) == 0) { wp[tid >> 6] = bp; wn[tid >> 6] = bn; wi[tid >> 6] = bi; }
    __syncthreads();
    if (tid == 0) {
      float fp2 = wp[0]; int fn2 = wn[0], fi2 = wi[0];
#pragma unroll
      for (int w2 = 1; w2 < 8; ++w2) {
        if (wp[w2] > fp2 || (wp[w2] == fp2 && wn[w2] < fn2)) { fp2 = wp[w2]; fn2 = wn[w2]; fi2 = wi[w2]; }
      }
      if (fp2 > 0.f) {
        out[r * NO + j] = (float)fn2;
        seln[r * NO + j] = fn2;
        sp[fi2] = -1.f;
      } else {
        out[r * NO + j] = -1.f;
        seln[r * NO + j] = -1;
      }
    }
    __syncthreads();
  }
}

// ---------- K6: exp_scores ----------

__global__ void k_expand(const float* __restrict__ scores,
                         const double* __restrict__ sums,
                         const float* __restrict__ rowstats,
                         const float* __restrict__ colmax,
                         const float* __restrict__ collse,
                         const int* __restrict__ seln,
                         float* __restrict__ out,
                         int N, int NO) {
  int b = blockIdx.x;
  int r2 = threadIdx.x;
  int n = seln[b];
  float v = 0.f;
  if (n >= 0) {
    float fmu, istd;
    get_mu_istd(sums, N, fmu, istd);
    float x = scores[(size_t)r2 * N + n];
    float v1 = (x - rowstats[r2]) * istd - rowstats[64 + r2];
    float v2 = (x - colmax[n]) * istd - collse[n];
    v = v1 + v2;
  }
  out[RR * NO + (size_t)b * RR + r2] = v;
}

// ---------- launch ----------

extern "C" void kernel_launch(void* const* d_in, const int* in_sizes, int n_in,
                              void* d_out, int out_size, void* d_ws, size_t ws_size,
                              hipStream_t stream) {
  const float* hs = (const float*)d_in[0];
  const float* es = (const float*)d_in[1];
  const float* W = (const float*)d_in[2];
  const void* mask = d_in[3];

  const int N = in_sizes[1] / DD;               // 200000
  const int NO = out_size / (RR * (1 + RR));    // 50

  char* ws = (char*)d_ws;
  size_t o = 0;
  float* scores = (float*)(ws + o);   o += (size_t)RR * N * 4;
  float* hsW = (float*)(ws + o);      o += RR * DD * 4;
  o = (o + 255) & ~(size_t)255;
  // contiguous zero region: sums(16) + cnt(256) + rowmax_u(512) + rowacc(512)
  double* sums = (double*)(ws + o);
  int* cnt = (int*)(ws + o + 16);
  unsigned* rowmax_u = (unsigned*)(ws + o + 16 + 256);
  float* rowacc = (float*)(ws + o + 16 + 256 + 512);
  size_t zero_off = o, zero_bytes = 16 + 256 + 512 + 512;
  o += 1536;
  float* rowstats = (float*)(ws + o); o += 256 * 4;
  o = (o + 255) & ~(size_t)255;
  float* colmax = (float*)(ws + o);   o += (size_t)N * 4;
  int* colargmax = (int*)(ws + o);    o += (size_t)N * 4;
  float* collse = (float*)(ws + o);   o += (size_t)N * 4;
  o = (o + 255) & ~(size_t)255;
  unsigned long long* mbits = (unsigned long long*)(ws + o); o += (size_t)N * 8;
  o = (o + 255) & ~(size_t)255;
  float* candx = (float*)(ws + o);    o += (size_t)RR * CAP * 4;
  int* candn = (int*)(ws + o);        o += (size_t)RR * CAP * 4;
  int* seln = (int*)(ws + o);         o += (size_t)RR * NO * 4;

  hipMemsetAsync(ws + zero_off, 0, zero_bytes, stream);

  const int NB = (N + 255) / 256;

  k_mask<<<NB, 256, 0, stream>>>(mask, mbits, N);
  k_hsw<<<RR, 256, 0, stream>>>(hs, W, hsW);
  k_scores<<<NB, 256, 0, stream>>>(es, hsW, mbits, scores, colmax, colargmax, sums,
                                   rowmax_u, N);
  k_colpass<<<NB, 256, 0, stream>>>(scores, colmax, colargmax, mbits, sums, rowmax_u,
                                    collse, rowacc, cnt, candx, candn, N);
  k_rowfin<<<1, 64, 0, stream>>>(rowacc, rowmax_u, rowstats);
  k_topk<<<RR, 512, 0, stream>>>(cnt, candx, candn, sums, rowstats, (float*)d_out, seln,
                                 N, NO);
  k_expand<<<RR * NO, 64, 0, stream>>>(scores, sums, rowstats, colmax, collse, seln,
                                       (float*)d_out, N, NO);
}